// Round 8
// baseline (335.737 us; speedup 1.0000x reference)
//
#include <hip/hip_runtime.h>
#include <hip/hip_bf16.h>
#include <math.h>

#define IN_DIM 512
#define HID    1024
#define NE     16
#define T_TOK  8192
#define NPAIR  (T_TOK*2)

typedef __attribute__((ext_vector_type(8))) short bf16x8;
typedef __attribute__((ext_vector_type(4))) float f32x4;

__device__ __forceinline__ unsigned short f2b(float f){
  unsigned u = __float_as_uint(f);
  u += 0x7FFF + ((u >> 16) & 1);           // round-to-nearest-even
  return (unsigned short)(u >> 16);
}
__device__ __forceinline__ float b2f(unsigned short u){
  return __uint_as_float(((unsigned)u) << 16);
}

// ---------------- prep: pack weights into MFMA B-fragment order ----------------
// in:  W [E][K][N] f32.  out: [e][nb(N/16)][kb(K/32)][lane(64)][8] bf16, so one wave
// load of 1KB at ((e*NB+nb)*KB+kb)*512 + lane*8 yields the B-frag for (nb,kb):
// lane l, elem j  <->  B[n = nb*16 + (l&15)][k = kb*32 + (l>>4)*8 + j].
__global__ __launch_bounds__(256) void packw_kernel(const float* __restrict__ in,
                                                    unsigned short* __restrict__ out,
                                                    int K, int N){
  int e  = blockIdx.z, nb = blockIdx.y;
  int kb = blockIdx.x*4 + (threadIdx.x >> 6);
  int l  = threadIdx.x & 63;
  int KB = K/32, NB = N/16;
  const float* src = in + (size_t)e*K*N + (size_t)(kb*32 + (l>>4)*8)*N + nb*16 + (l&15);
  unsigned short o[8];
  #pragma unroll
  for (int j=0;j<8;j++) o[j] = f2b(src[(size_t)j*N]);
  unsigned short* dst = out + (((size_t)e*NB + nb)*KB + kb)*512 + l*8;
  *(ushort4*)(dst)   = *(ushort4*)(o);
  *(ushort4*)(dst+4) = *(ushort4*)(o+4);
}

// ---------------- router: one wave per token; NO global atomics, NO residual write ----
__global__ __launch_bounds__(256) void router_kernel(
    const float* __restrict__ x, const float* __restrict__ Wr, const float* __restrict__ br,
    unsigned short* __restrict__ xb, int* __restrict__ eid, float* __restrict__ pw)
{
  int wid = threadIdx.x >> 6, lane = threadIdx.x & 63;
  int t = blockIdx.x*4 + wid;
  const float4* xr4 = (const float4*)(x + (size_t)t*IN_DIM);
  ushort4*      xb4 = (ushort4*)(xb + (size_t)t*IN_DIM);

  float acc[NE];
  #pragma unroll
  for (int i=0;i<NE;i++) acc[i]=0.f;

  #pragma unroll
  for (int j=0;j<2;j++){
    int f = j*64 + lane;
    float4 v = xr4[f];
    ushort4 o; o.x=f2b(v.x); o.y=f2b(v.y); o.z=f2b(v.z); o.w=f2b(v.w);
    xb4[f] = o;
    const float4* wr4 = (const float4*)(Wr + (size_t)(f*4)*NE);
    const float* vv = (const float*)&v;
    #pragma unroll
    for (int rr=0; rr<4; rr++){
      float xv = vv[rr];
      #pragma unroll
      for (int q=0;q<4;q++){
        float4 w = wr4[rr*4+q];
        acc[q*4+0] += xv*w.x; acc[q*4+1] += xv*w.y;
        acc[q*4+2] += xv*w.z; acc[q*4+3] += xv*w.w;
      }
    }
  }
  #pragma unroll
  for (int off=32; off>=1; off>>=1){
    #pragma unroll
    for (int i=0;i<NE;i++) acc[i] += __shfl_xor(acc[i], off, 64);
  }
  if (lane==0){
    #pragma unroll
    for (int i=0;i<NE;i++) acc[i] += br[i];
    int e0=0; float l0=acc[0];
    #pragma unroll
    for (int i=1;i<NE;i++) if (acc[i] > l0){ l0=acc[i]; e0=i; }
    int e1=-1; float l1=-3.0e38f;
    #pragma unroll
    for (int i=0;i<NE;i++) if (i!=e0 && acc[i] > l1){ l1=acc[i]; e1=i; }
    float w0 = 1.f/(1.f + __expf(l1 - l0));
    float w1 = 1.f - w0;
    pw[t*2+0] = w0; pw[t*2+1] = w1;
    eid[t*2+0] = e0; eid[t*2+1] = e1;
  }
}

// ---------------- bucket build: 16 blocks (one per expert), ballot-compact ----------
__global__ __launch_bounds__(1024) void bucket_kernel(const int* __restrict__ eid,
                                                      int* __restrict__ cnt,
                                                      int* __restrict__ bucket){
  int e = blockIdx.x;
  __shared__ int lbase;
  if (threadIdx.x == 0) lbase = 0;
  __syncthreads();
  int lane = threadIdx.x & 63, wid = threadIdx.x >> 6;
  int* be = bucket + e*T_TOK;
  for (int c = wid*64; c < NPAIR; c += 1024){
    int p = c + lane;
    bool ok = (eid[p] == e);
    unsigned long long m = __ballot(ok);
    int rank = __popcll(m & ((1ull << lane) - 1ull));
    int count = __popcll(m);
    int base = 0;
    if (lane == 0) base = atomicAdd(&lbase, count);
    base = __shfl(base, 0, 64);
    if (ok) be[base + rank] = p;
  }
  __syncthreads();
  if (threadIdx.x == 0) cnt[e] = lbase;
}

// ---------------- grouped GEMM: BARRIER-FREE, fragments direct from global ----------
// Block 64x128 (4 waves 2x2, wave-tile 32x64). No LDS, no __syncthreads: B-frags are
// 1KB coalesced reads from the packed layout; A-frags are per-lane 16B gathers. Manual
// depth-2 register pipeline; with no barrier the compiler keeps loads in flight with
// fine-grained vmcnt(N) (the drain that killed R3-R7 structures cannot occur).
// FIRST: A = xb[T,512] gathered by pair>>1; out = gelu(A@W1^T + b1) -> hb[pair][1024]
// !FIRST: A = hb gathered by pair; opb[pair][n] = bf16(pw[pair]*(A@W2^T + b2))
template<int KDIM, int NDIM, bool FIRST>
__global__ __launch_bounds__(256) void moe_gemm(
    const unsigned short* __restrict__ A,
    const unsigned short* __restrict__ Bp_,   // packed [e][nb][kb][lane][8]
    const float* __restrict__ bias,           // [E][NDIM]
    const int* __restrict__ cnt,
    const int* __restrict__ bucket,
    const float* __restrict__ pw,
    unsigned short* __restrict__ hb,
    unsigned short* __restrict__ opb)
{
  constexpr int KB = KDIM/32, NB = NDIM/16;
  int e  = blockIdx.z;
  int n0 = blockIdx.x * 128;
  int i0 = blockIdx.y * 64;
  int ce = cnt[e];
  if (i0 >= ce) return;

  int tid = threadIdx.x;
  int lane = tid & 63, wid = tid >> 6;
  int wm = (wid>>1)*32, wn = (wid&1)*64;
  int fr = lane & 15, fq8 = (lane>>4)*8;
  const int* buck = bucket + e*T_TOK;

  // A per-lane fragment base pointers (2 frags of 16 rows)
  const unsigned short* aP[2];
  #pragma unroll
  for (int s=0;s<2;s++){
    int pos  = i0 + wm + s*16 + fr;
    int pair = (pos < ce) ? buck[pos] : buck[i0];
    int row  = FIRST ? (pair >> 1) : pair;
    aP[s] = A + (size_t)row*KDIM + fq8;
  }
  // B packed fragment base pointers (4 frags of 16 cols)
  const unsigned short* bP[4];
  int nb0 = (n0 + wn) >> 4;
  #pragma unroll
  for (int u=0;u<4;u++)
    bP[u] = Bp_ + (((size_t)e*NB + nb0 + u)*KB)*512 + lane*8;

  f32x4 acc[2][4];
  #pragma unroll
  for (int a=0;a<2;a++)
    #pragma unroll
    for (int b=0;b<4;b++)
      #pragma unroll
      for (int j=0;j<4;j++) acc[a][b][j] = 0.f;

  // depth-2 register pipeline
  bf16x8 a0[2], a1[2], b0[4], b1[4];
  #pragma unroll
  for (int s=0;s<2;s++){ a0[s] = *(const bf16x8*)(aP[s]);
                         a1[s] = *(const bf16x8*)(aP[s] + 32); }
  #pragma unroll
  for (int u=0;u<4;u++){ b0[u] = *(const bf16x8*)(bP[u]);
                         b1[u] = *(const bf16x8*)(bP[u] + 512); }

  #pragma unroll 2
  for (int k = 0; k < KB; k += 2){
    bf16x8 ta[2], tb[4];
    bool ld0 = (k+2) < KB;
    if (ld0){
      #pragma unroll
      for (int s=0;s<2;s++) ta[s] = *(const bf16x8*)(aP[s] + (k+2)*32);
      #pragma unroll
      for (int u=0;u<4;u++) tb[u] = *(const bf16x8*)(bP[u] + (size_t)(k+2)*512);
    }
    #pragma unroll
    for (int s=0;s<2;s++)
      #pragma unroll
      for (int u=0;u<4;u++)
        acc[s][u] = __builtin_amdgcn_mfma_f32_16x16x32_bf16(a0[s], b0[u], acc[s][u], 0,0,0);
    if (ld0){
      #pragma unroll
      for (int s=0;s<2;s++) a0[s] = ta[s];
      #pragma unroll
      for (int u=0;u<4;u++) b0[u] = tb[u];
    }
    bool ld1 = (k+3) < KB;
    if (ld1){
      #pragma unroll
      for (int s=0;s<2;s++) ta[s] = *(const bf16x8*)(aP[s] + (k+3)*32);
      #pragma unroll
      for (int u=0;u<4;u++) tb[u] = *(const bf16x8*)(bP[u] + (size_t)(k+3)*512);
    }
    #pragma unroll
    for (int s=0;s<2;s++)
      #pragma unroll
      for (int u=0;u<4;u++)
        acc[s][u] = __builtin_amdgcn_mfma_f32_16x16x32_bf16(a1[s], b1[u], acc[s][u], 0,0,0);
    if (ld1){
      #pragma unroll
      for (int s=0;s<2;s++) a1[s] = ta[s];
      #pragma unroll
      for (int u=0;u<4;u++) b1[u] = tb[u];
    }
  }

  // epilogue: C/D layout col=lane&15, row=(lane>>4)*4+reg  [m89-verified]
  int fq = (lane>>4)*4;
  #pragma unroll
  for (int s=0;s<2;s++){
    #pragma unroll
    for (int i=0;i<4;i++){
      int row = wm + s*16 + fq + i;
      int pos = i0 + row;
      if (pos >= ce) continue;
      int pair = buck[pos];
      float w = FIRST ? 0.f : pw[pair];
      #pragma unroll
      for (int u=0;u<4;u++){
        int n = n0 + wn + u*16 + fr;
        float v = acc[s][u][i] + bias[e*NDIM + n];
        if (FIRST){
          float g = 0.5f*v*(1.f + erff(v*0.70710678118654752f));   // exact GELU
          hb[(size_t)pair*NDIM + n] = f2b(g);
        } else {
          opb[(size_t)pair*NDIM + n] = f2b(w*v);    // plain store, no atomics
        }
      }
    }
  }
}

// ---------------- combine: out = x + opb[2t] + opb[2t+1] (coalesced) ----------------
__global__ __launch_bounds__(256) void combine_kernel(const float* __restrict__ x,
                                                      const unsigned short* __restrict__ opb,
                                                      float* __restrict__ out){
  int i = blockIdx.x*256 + threadIdx.x;
  int t  = i >> 7;
  int c4 = i & 127;
  float4 v = ((const float4*)x)[i];
  ushort4 a = ((const ushort4*)opb)[(size_t)(2*t)*128 + c4];
  ushort4 b = ((const ushort4*)opb)[(size_t)(2*t+1)*128 + c4];
  v.x += b2f(a.x) + b2f(b.x);
  v.y += b2f(a.y) + b2f(b.y);
  v.z += b2f(a.z) + b2f(b.z);
  v.w += b2f(a.w) + b2f(b.w);
  ((float4*)out)[i] = v;
}

// ---------------- launch ----------------
extern "C" void kernel_launch(void* const* d_in, const int* in_sizes, int n_in,
                              void* d_out, int out_size, void* d_ws, size_t ws_size,
                              hipStream_t stream)
{
  const float* x  = (const float*)d_in[0];
  const float* Wr = (const float*)d_in[1];
  const float* br = (const float*)d_in[2];
  const float* W1 = (const float*)d_in[3];
  const float* b1 = (const float*)d_in[4];
  const float* W2 = (const float*)d_in[5];
  const float* b2 = (const float*)d_in[6];
  float* out = (float*)d_out;
  char* ws = (char*)d_ws;

  // ws layout (bytes) — identical footprint to the passing R1-R7 layout
  int*            cnt    = (int*)(ws + 0);            // 64 B
  int*            bucket = (int*)(ws + 1024);         // 16*8192*4 = 524288
  float*          pw     = (float*)(ws + 525312);     // 16384*4   = 65536
  unsigned short* xb     = (unsigned short*)(ws + 590848);    // 8192*512*2  = 8388608
  unsigned short* w1p    = (unsigned short*)(ws + 8979456);   // 16*512*1024*2 = 16777216
  unsigned short* w2p    = (unsigned short*)(ws + 25756672);  // 16777216
  unsigned short* hb     = (unsigned short*)(ws + 42533888);  // 16384*1024*2 = 33554432
  // aliases (stream-ordered lifetimes):
  //  eid at hb head: router writes, bucket reads, dead before GEMM1 writes hb
  //  opb in w1p region: w1p dead after GEMM1; opb = GEMM2 out, read by combine
  int*            eid    = (int*)(ws + 42533888);     // 16384*4 = 65536
  unsigned short* opb    = w1p;                       // 16384*512*2 = 16777216 (exact fit)

  router_kernel<<<T_TOK/4, 256, 0, stream>>>(x, Wr, br, xb, eid, pw);
  bucket_kernel<<<NE, 1024, 0, stream>>>(eid, cnt, bucket);
  // W1: K=512 (KB=16), N=1024 (NB=64). W2: K=1024 (KB=32), N=512 (NB=32).
  packw_kernel<<<dim3(16/4, 64, NE), 256, 0, stream>>>(W1, w1p, IN_DIM, HID);
  packw_kernel<<<dim3(32/4, 32, NE), 256, 0, stream>>>(W2, w2p, HID, IN_DIM);
  moe_gemm<IN_DIM, HID, true ><<<dim3(HID/128,    T_TOK/64, NE), 256, 0, stream>>>(
      xb, w1p, b1, cnt, bucket, pw, hb, opb);
  moe_gemm<HID, IN_DIM, false><<<dim3(IN_DIM/128, T_TOK/64, NE), 256, 0, stream>>>(
      hb, w2p, b2, cnt, bucket, pw, hb, opb);
  combine_kernel<<<(T_TOK*IN_DIM/4)/256, 256, 0, stream>>>(x, opb, out);
}